// Round 1
// baseline (366.106 us; speedup 1.0000x reference)
//
#include <hip/hip_runtime.h>
#include <hip/hip_bf16.h>

#define N_NODES 50000
#define IN_CH 64
#define HC 128          // HEADS * OUT_CH
#define CAP 64          // per-node bucket capacity (incl. self-loop slot 0)
#define NEG_SLOPE 0.2f
#define BN_EPS 1e-5f

// ---- ws layout (bytes) ----
// 0       : int   flag_int64
// 64      : float mean_sums[3]
// 192     : float mean_feat[128]
// 1024    : float bn_sums[256]   (sum[128], sumsq[128])
// 4096    : int   deg[N_NODES]
// 1<<18   : int   srcs[N_NODES*CAP]   (12.8 MB)
// 1<<24   : float xl[N_NODES*HC]      (25.6 MB)
// total ~41.6 MB

// ---------------------------------------------------------------- init + dtype sniff
__global__ __launch_bounds__(256) void k_init(const int* __restrict__ eidx,
                                              int* __restrict__ deg,
                                              float* __restrict__ mean_sums,
                                              float* __restrict__ bn_sums,
                                              int* __restrict__ flag) {
  int tid = blockIdx.x * 256 + threadIdx.x;
  if (tid < N_NODES) deg[tid] = 1;   // slot 0 reserved for the self-loop
  if (blockIdx.x == 0) {
    if (threadIdx.x < 3) mean_sums[threadIdx.x] = 0.f;
    if (threadIdx.x < 256) bn_sums[threadIdx.x] = 0.f;
    if (threadIdx.x < 64) {
      // int64 edge_index => odd 32-bit words are high words == 0 (indices < 50000)
      int w = eidx[2 * threadIdx.x + 1];
      unsigned long long nz = __ballot(w != 0);
      if (threadIdx.x == 0) flag[0] = (nz == 0ULL) ? 1 : 0;
    }
  }
}

// ---------------------------------------------------------------- xl = x@Wl (->ws), xr = x@Wr (->d_out)
__global__ __launch_bounds__(256) void k_gemm(const float* __restrict__ x,
                                              const float* __restrict__ Wl,
                                              const float* __restrict__ Wr,
                                              float* __restrict__ xl,
                                              float* __restrict__ xr_out) {
  __shared__ float xs[16][IN_CH];                 // 4 KB
  __shared__ __hip_bfloat162 wsm[IN_CH][128];     // 64 rows x 128 col-pairs = 32 KB
  const int t = threadIdx.x;
  const int row0 = blockIdx.x * 16;

  // stage W (both matrices, concatenated cols 0..255) as bf16 pairs
  for (int i = 0; i < 32; ++i) {
    int k = i * 2 + (t >> 7);       // 0..63
    int p = t & 127;                // pair index, col = 2p
    int cc = p * 2;
    float2 wv;
    if (cc < 128) wv = *(const float2*)(Wl + k * 128 + cc);
    else          wv = *(const float2*)(Wr + k * 128 + (cc - 128));
    wsm[k][p] = __float22bfloat162_rn(wv);
  }
  // stage x tile: 16 rows x 64 cols
  {
    int r = t >> 4, c4 = (t & 15) * 4;
    *(float4*)&xs[r][c4] = *(const float4*)(x + (row0 + r) * IN_CH + c4);
  }
  __syncthreads();

  const int ct = t & 63;        // col group: cols 4ct..4ct+3 of 256
  const int rt = t >> 6;        // row group: rows 4rt..4rt+3
  const int c4 = ct * 4;
  const int r4 = rt * 4;

  float acc[4][4];
  #pragma unroll
  for (int a = 0; a < 4; ++a)
    #pragma unroll
    for (int b = 0; b < 4; ++b) acc[a][b] = 0.f;

  #pragma unroll 8
  for (int k = 0; k < IN_CH; ++k) {
    uint2 wraw = *(const uint2*)&wsm[k][ct * 2];
    float2 f01 = __bfloat1622float2(*(__hip_bfloat162*)&wraw.x);
    float2 f23 = __bfloat1622float2(*(__hip_bfloat162*)&wraw.y);
    float wv[4] = {f01.x, f01.y, f23.x, f23.y};
    float xv[4] = {xs[r4][k], xs[r4 + 1][k], xs[r4 + 2][k], xs[r4 + 3][k]};
    #pragma unroll
    for (int a = 0; a < 4; ++a)
      #pragma unroll
      for (int b = 0; b < 4; ++b) acc[a][b] = fmaf(xv[a], wv[b], acc[a][b]);
  }

  #pragma unroll
  for (int a = 0; a < 4; ++a) {
    int row = row0 + r4 + a;
    float4 v = make_float4(acc[a][0], acc[a][1], acc[a][2], acc[a][3]);
    if (c4 < 128) *(float4*)(xl + row * HC + c4) = v;
    else          *(float4*)(xr_out + row * HC + (c4 - 128)) = v;
  }
}

// ---------------------------------------------------------------- edge pass: degree count, bucket scatter, pos-diff mean
__global__ __launch_bounds__(256) void k_edges(const int* __restrict__ eidx,
                                               const float* __restrict__ pos,
                                               int* __restrict__ deg,
                                               int* __restrict__ srcs,
                                               float* __restrict__ mean_sums,
                                               const int* __restrict__ flag,
                                               int E) {
  const bool w64 = flag[0] != 0;
  float sx = 0.f, sy = 0.f, sz = 0.f;
  const int stride = gridDim.x * blockDim.x;
  for (int e = blockIdx.x * blockDim.x + threadIdx.x; e < E; e += stride) {
    int s, d;
    if (w64) { s = eidx[2 * e]; d = eidx[2 * (E + e)]; }
    else     { s = eidx[e];     d = eidx[E + e]; }
    int old = atomicAdd(&deg[d], 1);
    if (old < CAP) srcs[d * CAP + old] = s;
    sx += pos[3 * s]     - pos[3 * d];
    sy += pos[3 * s + 1] - pos[3 * d + 1];
    sz += pos[3 * s + 2] - pos[3 * d + 2];
  }
  #pragma unroll
  for (int m = 1; m < 64; m <<= 1) {
    sx += __shfl_xor(sx, m); sy += __shfl_xor(sy, m); sz += __shfl_xor(sz, m);
  }
  __shared__ float red[4][3];
  int wave = threadIdx.x >> 6, lane = threadIdx.x & 63;
  if (lane == 0) { red[wave][0] = sx; red[wave][1] = sy; red[wave][2] = sz; }
  __syncthreads();
  if (threadIdx.x == 0) {
    float a = 0.f, b = 0.f, c = 0.f;
    for (int w = 0; w < 4; ++w) { a += red[w][0]; b += red[w][1]; c += red[w][2]; }
    unsafeAtomicAdd(&mean_sums[0], a);
    unsafeAtomicAdd(&mean_sums[1], b);
    unsafeAtomicAdd(&mean_sums[2], c);
  }
}

// ---------------------------------------------------------------- mean_feat = mean_attr @ W_edge
__global__ void k_meanfeat(const float* __restrict__ We,
                           const float* __restrict__ mean_sums,
                           float* __restrict__ mean_feat, int E) {
  int c = threadIdx.x;  // 128 threads
  float inv = 1.f / (float)E;
  float m0 = mean_sums[0] * inv, m1 = mean_sums[1] * inv, m2 = mean_sums[2] * inv;
  mean_feat[c] = m0 * We[c] + m1 * We[128 + c] + m2 * We[256 + c];
}

// ---------------------------------------------------------------- one wave per node: scores + softmax + aggregate
__global__ __launch_bounds__(256) void k_agg(const float* __restrict__ xl,
                                             float* __restrict__ xr_out,   // in: xr, out: pre-BN out
                                             const float* __restrict__ pos,
                                             const float* __restrict__ att,
                                             const float* __restrict__ We,
                                             const float* __restrict__ mean_feat,
                                             const int* __restrict__ srcs,
                                             const int* __restrict__ deg) {
  const int wave = threadIdx.x >> 6;
  const int lane = threadIdx.x & 63;
  const int i = blockIdx.x * 4 + wave;       // 12500*4 == 50000 exactly
  const int c = lane * 2;                    // channels c, c+1 ; head = lane/16

  const float2 xr2 = *(const float2*)(xr_out + i * HC + c);
  const float px = pos[3 * i], py = pos[3 * i + 1], pz = pos[3 * i + 2];
  const float2 at2 = *(const float2*)(att + c);
  const float w00 = We[c],        w01 = We[c + 1];
  const float w10 = We[128 + c],  w11 = We[128 + c + 1];
  const float w20 = We[256 + c],  w21 = We[256 + c + 1];

  float accx = 0.f, accy = 0.f, den = 0.f;
  const int di = min(deg[i], CAP);

  // slot 0: self-loop (src = i, edge feature = mean_feat)
  {
    const float2 mf2 = *(const float2*)(mean_feat + c);
    float2 xls = *(const float2*)(xl + i * HC + c);
    float tx = xls.x + xr2.x + mf2.x;
    float ty = xls.y + xr2.y + mf2.y;
    tx = fmaxf(tx, 0.f) + NEG_SLOPE * fminf(tx, 0.f);
    ty = fmaxf(ty, 0.f) + NEG_SLOPE * fminf(ty, 0.f);
    float sc = tx * at2.x + ty * at2.y;
    sc += __shfl_xor(sc, 1); sc += __shfl_xor(sc, 2);
    sc += __shfl_xor(sc, 4); sc += __shfl_xor(sc, 8);
    float p = __expf(sc);
    den += p;
    accx = fmaf(p, xls.x, accx);
    accy = fmaf(p, xls.y, accy);
  }

  for (int j = 1; j < di; ++j) {
    int s = srcs[i * CAP + j];
    float2 xls = *(const float2*)(xl + s * HC + c);
    float dx = pos[3 * s] - px, dy = pos[3 * s + 1] - py, dz = pos[3 * s + 2] - pz;
    float efx = dx * w00 + dy * w10 + dz * w20;
    float efy = dx * w01 + dy * w11 + dz * w21;
    float tx = xls.x + xr2.x + efx;
    float ty = xls.y + xr2.y + efy;
    tx = fmaxf(tx, 0.f) + NEG_SLOPE * fminf(tx, 0.f);
    ty = fmaxf(ty, 0.f) + NEG_SLOPE * fminf(ty, 0.f);
    float sc = tx * at2.x + ty * at2.y;
    sc += __shfl_xor(sc, 1); sc += __shfl_xor(sc, 2);
    sc += __shfl_xor(sc, 4); sc += __shfl_xor(sc, 8);
    float p = __expf(sc);
    den += p;
    accx = fmaf(p, xls.x, accx);
    accy = fmaf(p, xls.y, accy);
  }

  float inv = 1.f / (den + 1e-16f);
  float2 o; o.x = accx * inv; o.y = accy * inv;
  *(float2*)(xr_out + i * HC + c) = o;   // overwrite xr row with pre-BN output
}

// ---------------------------------------------------------------- BN stats
__global__ __launch_bounds__(128) void k_bnstats(const float* __restrict__ out,
                                                 float* __restrict__ bn_sums) {
  int c = threadIdx.x;   // 128
  float s = 0.f, ss = 0.f;
  for (int r = blockIdx.x; r < N_NODES; r += gridDim.x) {
    float v = out[r * HC + c];
    s += v; ss = fmaf(v, v, ss);
  }
  unsafeAtomicAdd(&bn_sums[c], s);
  unsafeAtomicAdd(&bn_sums[128 + c], ss);
}

// ---------------------------------------------------------------- BN apply (in place)
__global__ __launch_bounds__(256) void k_bnapply(float* __restrict__ out,
                                                 const float* __restrict__ bn_sums,
                                                 const float* __restrict__ gamma,
                                                 const float* __restrict__ beta,
                                                 int n4) {
  const int stride = gridDim.x * blockDim.x;
  const float invN = 1.f / (float)N_NODES;
  for (int i = blockIdx.x * blockDim.x + threadIdx.x; i < n4; i += stride) {
    int c = (i & 31) * 4;
    float4 v = ((float4*)out)[i];
    float4 s = *(const float4*)(bn_sums + c);
    float4 q = *(const float4*)(bn_sums + 128 + c);
    float4 g = *(const float4*)(gamma + c);
    float4 b = *(const float4*)(beta + c);
    float mu, var, rstd;
    mu = s.x * invN; var = q.x * invN - mu * mu; rstd = rsqrtf(var + BN_EPS);
    v.x = (v.x - mu) * rstd * g.x + b.x;
    mu = s.y * invN; var = q.y * invN - mu * mu; rstd = rsqrtf(var + BN_EPS);
    v.y = (v.y - mu) * rstd * g.y + b.y;
    mu = s.z * invN; var = q.z * invN - mu * mu; rstd = rsqrtf(var + BN_EPS);
    v.z = (v.z - mu) * rstd * g.z + b.z;
    mu = s.w * invN; var = q.w * invN - mu * mu; rstd = rsqrtf(var + BN_EPS);
    v.w = (v.w - mu) * rstd * g.w + b.w;
    ((float4*)out)[i] = v;
  }
}

extern "C" void kernel_launch(void* const* d_in, const int* in_sizes, int n_in,
                              void* d_out, int out_size, void* d_ws, size_t ws_size,
                              hipStream_t stream) {
  const float* x     = (const float*)d_in[0];
  const float* pos   = (const float*)d_in[1];
  const int*   eidx  = (const int*)d_in[2];
  const float* Wl    = (const float*)d_in[3];
  const float* Wr    = (const float*)d_in[4];
  const float* We    = (const float*)d_in[5];
  const float* att   = (const float*)d_in[6];
  const float* gamma = (const float*)d_in[7];
  const float* beta  = (const float*)d_in[8];
  float* out = (float*)d_out;
  const int E = in_sizes[2] / 2;

  char* ws = (char*)d_ws;
  int*   flag      = (int*)(ws + 0);
  float* mean_sums = (float*)(ws + 64);
  float* mean_feat = (float*)(ws + 192);
  float* bn_sums   = (float*)(ws + 1024);
  int*   deg       = (int*)(ws + 4096);
  int*   srcs      = (int*)(ws + (1 << 18));
  float* xl        = (float*)(ws + (1 << 24));

  k_init<<<(N_NODES + 255) / 256, 256, 0, stream>>>(eidx, deg, mean_sums, bn_sums, flag);
  k_gemm<<<N_NODES / 16, 256, 0, stream>>>(x, Wl, Wr, xl, out);
  k_edges<<<512, 256, 0, stream>>>(eidx, pos, deg, srcs, mean_sums, flag, E);
  k_meanfeat<<<1, 128, 0, stream>>>(We, mean_sums, mean_feat, E);
  k_agg<<<N_NODES / 4, 256, 0, stream>>>(xl, out, pos, att, We, mean_feat, srcs, deg);
  k_bnstats<<<250, 128, 0, stream>>>(out, bn_sums);
  k_bnapply<<<400, 256, 0, stream>>>(out, bn_sums, gamma, beta, out_size / 4);
}

// Round 2
// 329.752 us; speedup vs baseline: 1.1102x; 1.1102x over previous
//
#include <hip/hip_runtime.h>
#include <hip/hip_bf16.h>

#define N_NODES 50000
#define IN_CH 64
#define HC 128          // HEADS * OUT_CH
#define CAP 64          // per-node bucket capacity (incl. self-loop slot 0)
#define NEG_SLOPE 0.2f
#define BN_EPS 1e-5f

// ---- ws layout (bytes) ----
// 0       : int   flag_int64
// 64      : float mean_sums[3]
// 192     : float mean_feat[128]
// 1024    : float bn_sums[256]   (sum[128], sumsq[128])
// 4096    : int   deg[N_NODES]           (indeg+1; slot 0 = self-loop)
// 1<<18   : int   ocnt[N_NODES]          (outdeg)
// 1<<19   : int   srcs[N_NODES*CAP]      (12.8 MB)
// 1<<24   : uint  xl_bf[N_NODES*64]      (12.8 MB, bf16x2 per word)

// ---------------------------------------------------------------- init + dtype sniff
__global__ __launch_bounds__(256) void k_init(const int* __restrict__ eidx,
                                              int* __restrict__ deg,
                                              int* __restrict__ ocnt,
                                              float* __restrict__ mean_sums,
                                              float* __restrict__ bn_sums,
                                              int* __restrict__ flag) {
  int tid = blockIdx.x * 256 + threadIdx.x;
  if (tid < N_NODES) { deg[tid] = 1; ocnt[tid] = 0; }
  if (blockIdx.x == 0) {
    if (threadIdx.x < 3) mean_sums[threadIdx.x] = 0.f;
    if (threadIdx.x < 256) bn_sums[threadIdx.x] = 0.f;
    if (threadIdx.x < 64) {
      // int64 edge_index => odd 32-bit words (high words) all zero (indices < 50000)
      int w = eidx[2 * threadIdx.x + 1];
      unsigned long long nz = __ballot(w != 0);
      if (threadIdx.x == 0) flag[0] = (nz == 0ULL) ? 1 : 0;
    }
  }
}

// ---------------------------------------------------------------- xl = x@Wl (bf16 ->ws), xr = x@Wr (f32 ->d_out)
__global__ __launch_bounds__(256) void k_gemm(const float* __restrict__ x,
                                              const float* __restrict__ Wl,
                                              const float* __restrict__ Wr,
                                              unsigned int* __restrict__ xl_bf,
                                              float* __restrict__ xr_out) {
  __shared__ float xs[16][IN_CH];                 // 4 KB
  __shared__ __hip_bfloat162 wsm[IN_CH][128];     // 32 KB
  const int t = threadIdx.x;
  const int row0 = blockIdx.x * 16;

  for (int i = 0; i < 32; ++i) {
    int k = i * 2 + (t >> 7);
    int p = t & 127;
    int cc = p * 2;
    float2 wv;
    if (cc < 128) wv = *(const float2*)(Wl + k * 128 + cc);
    else          wv = *(const float2*)(Wr + k * 128 + (cc - 128));
    wsm[k][p] = __float22bfloat162_rn(wv);
  }
  {
    int r = t >> 4, c4 = (t & 15) * 4;
    *(float4*)&xs[r][c4] = *(const float4*)(x + (row0 + r) * IN_CH + c4);
  }
  __syncthreads();

  const int ct = t & 63;
  const int rt = t >> 6;
  const int c4 = ct * 4;
  const int r4 = rt * 4;

  float acc[4][4];
  #pragma unroll
  for (int a = 0; a < 4; ++a)
    #pragma unroll
    for (int b = 0; b < 4; ++b) acc[a][b] = 0.f;

  #pragma unroll 8
  for (int k = 0; k < IN_CH; ++k) {
    uint2 wraw = *(const uint2*)&wsm[k][ct * 2];
    float2 f01 = __bfloat1622float2(*(__hip_bfloat162*)&wraw.x);
    float2 f23 = __bfloat1622float2(*(__hip_bfloat162*)&wraw.y);
    float wv[4] = {f01.x, f01.y, f23.x, f23.y};
    float xv[4] = {xs[r4][k], xs[r4 + 1][k], xs[r4 + 2][k], xs[r4 + 3][k]};
    #pragma unroll
    for (int a = 0; a < 4; ++a)
      #pragma unroll
      for (int b = 0; b < 4; ++b) acc[a][b] = fmaf(xv[a], wv[b], acc[a][b]);
  }

  #pragma unroll
  for (int a = 0; a < 4; ++a) {
    int row = row0 + r4 + a;
    if (c4 < 128) {
      __hip_bfloat162 b01 = __float22bfloat162_rn(make_float2(acc[a][0], acc[a][1]));
      __hip_bfloat162 b23 = __float22bfloat162_rn(make_float2(acc[a][2], acc[a][3]));
      uint2 u;
      u.x = *(unsigned int*)&b01;
      u.y = *(unsigned int*)&b23;
      *(uint2*)(xl_bf + row * 64 + (c4 >> 1)) = u;
    } else {
      float4 v = make_float4(acc[a][0], acc[a][1], acc[a][2], acc[a][3]);
      *(float4*)(xr_out + row * HC + (c4 - 128)) = v;
    }
  }
}

// ---------------------------------------------------------------- edge pass: degree counts + bucket scatter (no pos reads)
__global__ __launch_bounds__(256) void k_edges(const int* __restrict__ eidx,
                                               int* __restrict__ deg,
                                               int* __restrict__ ocnt,
                                               int* __restrict__ srcs,
                                               const int* __restrict__ flag,
                                               int E) {
  const bool w64 = flag[0] != 0;
  const int stride = gridDim.x * blockDim.x;
  for (int e = blockIdx.x * blockDim.x + threadIdx.x; e < E; e += stride) {
    int s, d;
    if (w64) { s = eidx[2 * e]; d = eidx[2 * (E + e)]; }
    else     { s = eidx[e];     d = eidx[E + e]; }
    int old = atomicAdd(&deg[d], 1);
    if (old < CAP) srcs[d * CAP + old] = s;
    atomicAdd(&ocnt[s], 1);
  }
}

// ---------------------------------------------------------------- mean_sums = sum_n pos[n]*(outdeg-indeg)
__global__ __launch_bounds__(256) void k_nodemean(const float* __restrict__ pos,
                                                  const int* __restrict__ deg,
                                                  const int* __restrict__ ocnt,
                                                  float* __restrict__ mean_sums) {
  float sx = 0.f, sy = 0.f, sz = 0.f;
  const int stride = gridDim.x * blockDim.x;
  for (int n = blockIdx.x * blockDim.x + threadIdx.x; n < N_NODES; n += stride) {
    float net = (float)(ocnt[n] - (deg[n] - 1));
    sx = fmaf(pos[3 * n],     net, sx);
    sy = fmaf(pos[3 * n + 1], net, sy);
    sz = fmaf(pos[3 * n + 2], net, sz);
  }
  #pragma unroll
  for (int m = 1; m < 64; m <<= 1) {
    sx += __shfl_xor(sx, m); sy += __shfl_xor(sy, m); sz += __shfl_xor(sz, m);
  }
  __shared__ float red[4][3];
  int wave = threadIdx.x >> 6, lane = threadIdx.x & 63;
  if (lane == 0) { red[wave][0] = sx; red[wave][1] = sy; red[wave][2] = sz; }
  __syncthreads();
  if (threadIdx.x == 0) {
    float a = 0.f, b = 0.f, c = 0.f;
    for (int w = 0; w < 4; ++w) { a += red[w][0]; b += red[w][1]; c += red[w][2]; }
    unsafeAtomicAdd(&mean_sums[0], a);
    unsafeAtomicAdd(&mean_sums[1], b);
    unsafeAtomicAdd(&mean_sums[2], c);
  }
}

// ---------------------------------------------------------------- mean_feat = mean_attr @ W_edge
__global__ void k_meanfeat(const float* __restrict__ We,
                           const float* __restrict__ mean_sums,
                           float* __restrict__ mean_feat, int E) {
  int c = threadIdx.x;  // 128 threads
  float inv = 1.f / (float)E;
  float m0 = mean_sums[0] * inv, m1 = mean_sums[1] * inv, m2 = mean_sums[2] * inv;
  mean_feat[c] = m0 * We[c] + m1 * We[128 + c] + m2 * We[256 + c];
}

// ---------------------------------------------------------------- per-edge score + accumulate helper
__device__ __forceinline__ void edge_acc(unsigned int raw,
                                         float dx, float dy, float dz,
                                         float2 xr2, float2 at2,
                                         float w00, float w01, float w10,
                                         float w11, float w20, float w21,
                                         float& accx, float& accy, float& den) {
  float2 xls = __bfloat1622float2(*(__hip_bfloat162*)&raw);
  float efx = dx * w00 + dy * w10 + dz * w20;
  float efy = dx * w01 + dy * w11 + dz * w21;
  float tx = xls.x + xr2.x + efx;
  float ty = xls.y + xr2.y + efy;
  tx = fmaxf(tx, 0.f) + NEG_SLOPE * fminf(tx, 0.f);
  ty = fmaxf(ty, 0.f) + NEG_SLOPE * fminf(ty, 0.f);
  float sc = tx * at2.x + ty * at2.y;
  sc += __shfl_xor(sc, 1); sc += __shfl_xor(sc, 2);
  sc += __shfl_xor(sc, 4); sc += __shfl_xor(sc, 8);
  float p = __expf(sc);
  den += p;
  accx = fmaf(p, xls.x, accx);
  accy = fmaf(p, xls.y, accy);
}

// ---------------------------------------------------------------- one wave per node: scores + softmax + aggregate
__global__ __launch_bounds__(256) void k_agg(const unsigned int* __restrict__ xl_bf,
                                             float* __restrict__ xr_out,   // in: xr, out: pre-BN out
                                             const float* __restrict__ pos,
                                             const float* __restrict__ att,
                                             const float* __restrict__ We,
                                             const float* __restrict__ mean_feat,
                                             const int* __restrict__ srcs,
                                             const int* __restrict__ deg) {
  const int wave = threadIdx.x >> 6;
  const int lane = threadIdx.x & 63;
  const int i = blockIdx.x * 4 + wave;       // 12500*4 == 50000 exactly
  const int c = lane * 2;                    // channels c, c+1 ; head = lane/16

  const float2 xr2 = *(const float2*)(xr_out + i * HC + c);
  const float px = pos[3 * i], py = pos[3 * i + 1], pz = pos[3 * i + 2];
  const float2 at2 = *(const float2*)(att + c);
  const float w00 = We[c],        w01 = We[c + 1];
  const float w10 = We[128 + c],  w11 = We[128 + c + 1];
  const float w20 = We[256 + c],  w21 = We[256 + c + 1];

  float accx = 0.f, accy = 0.f, den = 0.f;
  const int di = min(deg[i], CAP);
  const int base = i * CAP;

  // slot 0: self-loop (src = i, edge feature = mean_feat)
  {
    unsigned int raw = xl_bf[(i << 6) + lane];
    float2 xls = __bfloat1622float2(*(__hip_bfloat162*)&raw);
    const float2 mf2 = *(const float2*)(mean_feat + c);
    float tx = xls.x + xr2.x + mf2.x;
    float ty = xls.y + xr2.y + mf2.y;
    tx = fmaxf(tx, 0.f) + NEG_SLOPE * fminf(tx, 0.f);
    ty = fmaxf(ty, 0.f) + NEG_SLOPE * fminf(ty, 0.f);
    float sc = tx * at2.x + ty * at2.y;
    sc += __shfl_xor(sc, 1); sc += __shfl_xor(sc, 2);
    sc += __shfl_xor(sc, 4); sc += __shfl_xor(sc, 8);
    float p = __expf(sc);
    den += p;
    accx = fmaf(p, xls.x, accx);
    accy = fmaf(p, xls.y, accy);
  }

  int j = 1;
  // 4x unrolled: batch the index loads, then 4 independent gather chains
  for (; j + 4 <= di; j += 4) {
    int s0 = srcs[base + j];
    int s1 = srcs[base + j + 1];
    int s2 = srcs[base + j + 2];
    int s3 = srcs[base + j + 3];
    unsigned int r0 = xl_bf[(s0 << 6) + lane];
    unsigned int r1 = xl_bf[(s1 << 6) + lane];
    unsigned int r2 = xl_bf[(s2 << 6) + lane];
    unsigned int r3 = xl_bf[(s3 << 6) + lane];
    float ax0 = pos[3 * s0] - px, ay0 = pos[3 * s0 + 1] - py, az0 = pos[3 * s0 + 2] - pz;
    float ax1 = pos[3 * s1] - px, ay1 = pos[3 * s1 + 1] - py, az1 = pos[3 * s1 + 2] - pz;
    float ax2 = pos[3 * s2] - px, ay2 = pos[3 * s2 + 1] - py, az2 = pos[3 * s2 + 2] - pz;
    float ax3 = pos[3 * s3] - px, ay3 = pos[3 * s3 + 1] - py, az3 = pos[3 * s3 + 2] - pz;
    edge_acc(r0, ax0, ay0, az0, xr2, at2, w00, w01, w10, w11, w20, w21, accx, accy, den);
    edge_acc(r1, ax1, ay1, az1, xr2, at2, w00, w01, w10, w11, w20, w21, accx, accy, den);
    edge_acc(r2, ax2, ay2, az2, xr2, at2, w00, w01, w10, w11, w20, w21, accx, accy, den);
    edge_acc(r3, ax3, ay3, az3, xr2, at2, w00, w01, w10, w11, w20, w21, accx, accy, den);
  }
  for (; j < di; ++j) {
    int s = srcs[base + j];
    unsigned int r = xl_bf[(s << 6) + lane];
    float ax = pos[3 * s] - px, ay = pos[3 * s + 1] - py, az = pos[3 * s + 2] - pz;
    edge_acc(r, ax, ay, az, xr2, at2, w00, w01, w10, w11, w20, w21, accx, accy, den);
  }

  float inv = 1.f / (den + 1e-16f);
  float2 o; o.x = accx * inv; o.y = accy * inv;
  *(float2*)(xr_out + i * HC + c) = o;   // overwrite xr row with pre-BN output
}

// ---------------------------------------------------------------- BN stats
__global__ __launch_bounds__(128) void k_bnstats(const float* __restrict__ out,
                                                 float* __restrict__ bn_sums) {
  int c = threadIdx.x;   // 128
  float s = 0.f, ss = 0.f;
  for (int r = blockIdx.x; r < N_NODES; r += gridDim.x) {
    float v = out[r * HC + c];
    s += v; ss = fmaf(v, v, ss);
  }
  unsafeAtomicAdd(&bn_sums[c], s);
  unsafeAtomicAdd(&bn_sums[128 + c], ss);
}

// ---------------------------------------------------------------- BN apply (in place)
__global__ __launch_bounds__(256) void k_bnapply(float* __restrict__ out,
                                                 const float* __restrict__ bn_sums,
                                                 const float* __restrict__ gamma,
                                                 const float* __restrict__ beta,
                                                 int n4) {
  const int stride = gridDim.x * blockDim.x;
  const float invN = 1.f / (float)N_NODES;
  for (int i = blockIdx.x * blockDim.x + threadIdx.x; i < n4; i += stride) {
    int c = (i & 31) * 4;
    float4 v = ((float4*)out)[i];
    float4 s = *(const float4*)(bn_sums + c);
    float4 q = *(const float4*)(bn_sums + 128 + c);
    float4 g = *(const float4*)(gamma + c);
    float4 b = *(const float4*)(beta + c);
    float mu, var, rstd;
    mu = s.x * invN; var = q.x * invN - mu * mu; rstd = rsqrtf(var + BN_EPS);
    v.x = (v.x - mu) * rstd * g.x + b.x;
    mu = s.y * invN; var = q.y * invN - mu * mu; rstd = rsqrtf(var + BN_EPS);
    v.y = (v.y - mu) * rstd * g.y + b.y;
    mu = s.z * invN; var = q.z * invN - mu * mu; rstd = rsqrtf(var + BN_EPS);
    v.z = (v.z - mu) * rstd * g.z + b.z;
    mu = s.w * invN; var = q.w * invN - mu * mu; rstd = rsqrtf(var + BN_EPS);
    v.w = (v.w - mu) * rstd * g.w + b.w;
    ((float4*)out)[i] = v;
  }
}

extern "C" void kernel_launch(void* const* d_in, const int* in_sizes, int n_in,
                              void* d_out, int out_size, void* d_ws, size_t ws_size,
                              hipStream_t stream) {
  const float* x     = (const float*)d_in[0];
  const float* pos   = (const float*)d_in[1];
  const int*   eidx  = (const int*)d_in[2];
  const float* Wl    = (const float*)d_in[3];
  const float* Wr    = (const float*)d_in[4];
  const float* We    = (const float*)d_in[5];
  const float* att   = (const float*)d_in[6];
  const float* gamma = (const float*)d_in[7];
  const float* beta  = (const float*)d_in[8];
  float* out = (float*)d_out;
  const int E = in_sizes[2] / 2;

  char* ws = (char*)d_ws;
  int*   flag      = (int*)(ws + 0);
  float* mean_sums = (float*)(ws + 64);
  float* mean_feat = (float*)(ws + 192);
  float* bn_sums   = (float*)(ws + 1024);
  int*   deg       = (int*)(ws + 4096);
  int*   ocnt      = (int*)(ws + (1 << 18));
  int*   srcs      = (int*)(ws + (1 << 19));
  unsigned int* xl_bf = (unsigned int*)(ws + (1 << 24));

  k_init<<<(N_NODES + 255) / 256, 256, 0, stream>>>(eidx, deg, ocnt, mean_sums, bn_sums, flag);
  k_gemm<<<N_NODES / 16, 256, 0, stream>>>(x, Wl, Wr, xl_bf, out);
  k_edges<<<512, 256, 0, stream>>>(eidx, deg, ocnt, srcs, flag, E);
  k_nodemean<<<128, 256, 0, stream>>>(pos, deg, ocnt, mean_sums);
  k_meanfeat<<<1, 128, 0, stream>>>(We, mean_sums, mean_feat, E);
  k_agg<<<N_NODES / 4, 256, 0, stream>>>(xl_bf, out, pos, att, We, mean_feat, srcs, deg);
  k_bnstats<<<250, 128, 0, stream>>>(out, bn_sums);
  k_bnapply<<<400, 256, 0, stream>>>(out, bn_sums, gamma, beta, out_size / 4);
}

// Round 3
// 288.874 us; speedup vs baseline: 1.2674x; 1.1415x over previous
//
#include <hip/hip_runtime.h>
#include <hip/hip_bf16.h>

#define N_NODES 50000
#define IN_CH 64
#define HC 128          // HEADS * OUT_CH
#define CAP 64          // per-node bucket capacity (incl. self-loop slot 0)
#define NEG_SLOPE 0.2f
#define BN_EPS 1e-5f

// ---- ws layout (bytes) ----
// 0       : int   flag_int64
// 64      : float mean_sums[3]
// 1024    : float bn_sums[256]   (sum[128], sumsq[128])
// 4096    : int   deg[N_NODES]           (indeg+1; slot 0 = self-loop)
// 1<<18   : int   ocnt[N_NODES]          (outdeg)
// 1<<19   : int   srcs[N_NODES*CAP]      (12.8 MB)
// 1<<24   : uint  xl_bf[N_NODES*64]      (12.8 MB, bf16x2 per word)

// ---------------------------------------------------------------- gemm + fused init
// xl = x@Wl (bf16 ->ws), xr = x@Wr (f32 ->d_out); blocks also init deg/ocnt/bn/flag
__global__ __launch_bounds__(256) void k_gemm(const float* __restrict__ x,
                                              const float* __restrict__ Wl,
                                              const float* __restrict__ Wr,
                                              unsigned int* __restrict__ xl_bf,
                                              float* __restrict__ xr_out,
                                              int* __restrict__ deg,
                                              int* __restrict__ ocnt,
                                              float* __restrict__ mean_sums,
                                              float* __restrict__ bn_sums,
                                              int* __restrict__ flag,
                                              const int* __restrict__ eidx) {
  // ---- fused init (independent of gemm work) ----
  {
    int gtid = blockIdx.x * 256 + threadIdx.x;
    if (gtid < N_NODES) { deg[gtid] = 1; ocnt[gtid] = 0; }
    if (gtid < 256) bn_sums[gtid] = 0.f;
    if (gtid < 3) mean_sums[gtid] = 0.f;
    if (blockIdx.x == 0 && threadIdx.x < 64) {
      // int64 edge_index => odd 32-bit words (high words) all zero (indices < 50000)
      int w = eidx[2 * threadIdx.x + 1];
      unsigned long long nz = __ballot(w != 0);
      if (threadIdx.x == 0) flag[0] = (nz == 0ULL) ? 1 : 0;
    }
  }

  __shared__ float xs[16][IN_CH];                 // 4 KB
  __shared__ __hip_bfloat162 wsm[IN_CH][128];     // 32 KB
  const int t = threadIdx.x;
  const int row0 = blockIdx.x * 16;

  for (int i = 0; i < 32; ++i) {
    int k = i * 2 + (t >> 7);
    int p = t & 127;
    int cc = p * 2;
    float2 wv;
    if (cc < 128) wv = *(const float2*)(Wl + k * 128 + cc);
    else          wv = *(const float2*)(Wr + k * 128 + (cc - 128));
    wsm[k][p] = __float22bfloat162_rn(wv);
  }
  {
    int r = t >> 4, c4 = (t & 15) * 4;
    *(float4*)&xs[r][c4] = *(const float4*)(x + (row0 + r) * IN_CH + c4);
  }
  __syncthreads();

  const int ct = t & 63;
  const int rt = t >> 6;
  const int c4 = ct * 4;
  const int r4 = rt * 4;

  float acc[4][4];
  #pragma unroll
  for (int a = 0; a < 4; ++a)
    #pragma unroll
    for (int b = 0; b < 4; ++b) acc[a][b] = 0.f;

  #pragma unroll 8
  for (int k = 0; k < IN_CH; ++k) {
    uint2 wraw = *(const uint2*)&wsm[k][ct * 2];
    float2 f01 = __bfloat1622float2(*(__hip_bfloat162*)&wraw.x);
    float2 f23 = __bfloat1622float2(*(__hip_bfloat162*)&wraw.y);
    float wv[4] = {f01.x, f01.y, f23.x, f23.y};
    float xv[4] = {xs[r4][k], xs[r4 + 1][k], xs[r4 + 2][k], xs[r4 + 3][k]};
    #pragma unroll
    for (int a = 0; a < 4; ++a)
      #pragma unroll
      for (int b = 0; b < 4; ++b) acc[a][b] = fmaf(xv[a], wv[b], acc[a][b]);
  }

  #pragma unroll
  for (int a = 0; a < 4; ++a) {
    int row = row0 + r4 + a;
    if (c4 < 128) {
      __hip_bfloat162 b01 = __float22bfloat162_rn(make_float2(acc[a][0], acc[a][1]));
      __hip_bfloat162 b23 = __float22bfloat162_rn(make_float2(acc[a][2], acc[a][3]));
      uint2 u;
      u.x = *(unsigned int*)&b01;
      u.y = *(unsigned int*)&b23;
      *(uint2*)(xl_bf + row * 64 + (c4 >> 1)) = u;
    } else {
      float4 v = make_float4(acc[a][0], acc[a][1], acc[a][2], acc[a][3]);
      *(float4*)(xr_out + row * HC + (c4 - 128)) = v;
    }
  }
}

// ---------------------------------------------------------------- edge pass: 2 edges/thread, counts + bucket scatter
__global__ __launch_bounds__(256) void k_edges(const int* __restrict__ eidx,
                                               int* __restrict__ deg,
                                               int* __restrict__ ocnt,
                                               int* __restrict__ srcs,
                                               const int* __restrict__ flag,
                                               int E) {
  const bool w64 = flag[0] != 0;
  const int stride = gridDim.x * blockDim.x;
  const int npair = (E + 1) >> 1;
  for (int e2 = blockIdx.x * blockDim.x + threadIdx.x; e2 < npair; e2 += stride) {
    int e0 = e2 * 2;
    bool has1 = (e0 + 1) < E;
    int s0, s1, d0, d1;
    if (w64) {
      int4 sv = *(const int4*)(eidx + 2 * e0);
      int4 dv = *(const int4*)(eidx + 2 * E + 2 * e0);
      s0 = sv.x; s1 = sv.z; d0 = dv.x; d1 = dv.z;
    } else {
      int2 sv = *(const int2*)(eidx + e0);
      int2 dv = *(const int2*)(eidx + E + e0);
      s0 = sv.x; s1 = sv.y; d0 = dv.x; d1 = dv.y;
    }
    int o0 = atomicAdd(&deg[d0], 1);
    if (o0 < CAP) srcs[d0 * CAP + o0] = s0;
    atomicAdd(&ocnt[s0], 1);
    if (has1) {
      int o1 = atomicAdd(&deg[d1], 1);
      if (o1 < CAP) srcs[d1 * CAP + o1] = s1;
      atomicAdd(&ocnt[s1], 1);
    }
  }
}

// ---------------------------------------------------------------- mean_sums = sum_n pos[n]*(outdeg-indeg)
__global__ __launch_bounds__(256) void k_nodemean(const float* __restrict__ pos,
                                                  const int* __restrict__ deg,
                                                  const int* __restrict__ ocnt,
                                                  float* __restrict__ mean_sums) {
  float sx = 0.f, sy = 0.f, sz = 0.f;
  const int stride = gridDim.x * blockDim.x;
  for (int n = blockIdx.x * blockDim.x + threadIdx.x; n < N_NODES; n += stride) {
    float net = (float)(ocnt[n] - (deg[n] - 1));
    sx = fmaf(pos[3 * n],     net, sx);
    sy = fmaf(pos[3 * n + 1], net, sy);
    sz = fmaf(pos[3 * n + 2], net, sz);
  }
  #pragma unroll
  for (int m = 1; m < 64; m <<= 1) {
    sx += __shfl_xor(sx, m); sy += __shfl_xor(sy, m); sz += __shfl_xor(sz, m);
  }
  __shared__ float red[4][3];
  int wave = threadIdx.x >> 6, lane = threadIdx.x & 63;
  if (lane == 0) { red[wave][0] = sx; red[wave][1] = sy; red[wave][2] = sz; }
  __syncthreads();
  if (threadIdx.x == 0) {
    float a = 0.f, b = 0.f, c = 0.f;
    for (int w = 0; w < 4; ++w) { a += red[w][0]; b += red[w][1]; c += red[w][2]; }
    unsafeAtomicAdd(&mean_sums[0], a);
    unsafeAtomicAdd(&mean_sums[1], b);
    unsafeAtomicAdd(&mean_sums[2], c);
  }
}

// ---------------------------------------------------------------- per-edge (half-wave, 4 ch/lane) helper
__device__ __forceinline__ void edge4(int s, float dx, float dy, float dz, bool valid,
                                      const unsigned int* __restrict__ xl_bf, int l5,
                                      float4 xr4, float4 at4, float4 w0, float4 w1, float4 w2,
                                      float& a0, float& a1, float& a2, float& a3, float& den) {
  uint2 raw = *(const uint2*)(xl_bf + (s << 6) + (l5 << 1));
  float2 x01 = __bfloat1622float2(*(__hip_bfloat162*)&raw.x);
  float2 x23 = __bfloat1622float2(*(__hip_bfloat162*)&raw.y);
  float t0 = x01.x + xr4.x; t0 = fmaf(dx, w0.x, t0); t0 = fmaf(dy, w1.x, t0); t0 = fmaf(dz, w2.x, t0);
  float t1 = x01.y + xr4.y; t1 = fmaf(dx, w0.y, t1); t1 = fmaf(dy, w1.y, t1); t1 = fmaf(dz, w2.y, t1);
  float t2 = x23.x + xr4.z; t2 = fmaf(dx, w0.z, t2); t2 = fmaf(dy, w1.z, t2); t2 = fmaf(dz, w2.z, t2);
  float t3 = x23.y + xr4.w; t3 = fmaf(dx, w0.w, t3); t3 = fmaf(dy, w1.w, t3); t3 = fmaf(dz, w2.w, t3);
  float l0 = fmaf(NEG_SLOPE, fminf(t0, 0.f), fmaxf(t0, 0.f));
  float l1 = fmaf(NEG_SLOPE, fminf(t1, 0.f), fmaxf(t1, 0.f));
  float l2 = fmaf(NEG_SLOPE, fminf(t2, 0.f), fmaxf(t2, 0.f));
  float l3 = fmaf(NEG_SLOPE, fminf(t3, 0.f), fmaxf(t3, 0.f));
  float sc = l0 * at4.x;
  sc = fmaf(l1, at4.y, sc); sc = fmaf(l2, at4.z, sc); sc = fmaf(l3, at4.w, sc);
  sc += __shfl_xor(sc, 1); sc += __shfl_xor(sc, 2); sc += __shfl_xor(sc, 4);  // 8 lanes = 1 head
  float e = __expf(sc);
  float p = valid ? e : 0.f;
  den += p;
  a0 = fmaf(p, x01.x, a0); a1 = fmaf(p, x01.y, a1);
  a2 = fmaf(p, x23.x, a2); a3 = fmaf(p, x23.y, a3);
}

// ---------------------------------------------------------------- one wave = 2 edges at a time, persistent over nodes
__global__ __launch_bounds__(256) void k_agg(const unsigned int* __restrict__ xl_bf,
                                             float* __restrict__ xr_out,   // in: xr, out: pre-BN out
                                             const float* __restrict__ pos,
                                             const float* __restrict__ att,
                                             const float* __restrict__ We,
                                             const float* __restrict__ mean_sums,
                                             const int* __restrict__ srcs,
                                             const int* __restrict__ deg,
                                             float invE) {
  const int lane = threadIdx.x & 63;
  const int half = lane >> 5;
  const int l5 = lane & 31;
  const int c = l5 << 2;               // 4 channels per lane; head = l5>>3

  const float4 at4 = *(const float4*)(att + c);
  const float4 w0 = *(const float4*)(We + c);
  const float4 w1 = *(const float4*)(We + 128 + c);
  const float4 w2 = *(const float4*)(We + 256 + c);
  const float m0 = mean_sums[0] * invE;
  const float m1 = mean_sums[1] * invE;
  const float m2 = mean_sums[2] * invE;

  const int gw = blockIdx.x * 4 + (threadIdx.x >> 6);
  const int W = gridDim.x * 4;

  for (int i = gw; i < N_NODES; i += W) {
    const float4 xr4 = *(const float4*)(xr_out + i * HC + c);
    const float px = pos[3 * i], py = pos[3 * i + 1], pz = pos[3 * i + 2];
    const int di = min(deg[i], CAP);
    const int sreg = srcs[i * CAP + lane];   // whole bucket row staged in registers
    float a0 = 0.f, a1 = 0.f, a2 = 0.f, a3 = 0.f, den = 0.f;

    // peeled first iteration: slots 0..3 (slot 0 = self-loop, dx = mean_attr)
    {
      int sA = __shfl(sreg, 1);
      if (half == 0) sA = i;
      bool vA = half < di;               // half1 invalid iff di==1
      if (!vA) sA = i;
      int jB = 2 + half;
      int sB = __shfl(sreg, jB);
      bool vB = jB < di;
      if (!vB) sB = i;
      float pax = pos[3 * sA], pay = pos[3 * sA + 1], paz = pos[3 * sA + 2];
      float pbx = pos[3 * sB], pby = pos[3 * sB + 1], pbz = pos[3 * sB + 2];
      float dxA = (half == 0) ? m0 : pax - px;
      float dyA = (half == 0) ? m1 : pay - py;
      float dzA = (half == 0) ? m2 : paz - pz;
      edge4(sA, dxA, dyA, dzA, vA, xl_bf, l5, xr4, at4, w0, w1, w2, a0, a1, a2, a3, den);
      edge4(sB, pbx - px, pby - py, pbz - pz, vB, xl_bf, l5, xr4, at4, w0, w1, w2, a0, a1, a2, a3, den);
    }

    for (int j = 4; j < di; j += 4) {
      int jA = j + half;
      int jB = j + 2 + half;
      int sA = __shfl(sreg, jA);
      int sB = __shfl(sreg, jB);
      bool vA = jA < di;
      bool vB = jB < di;
      if (!vA) sA = i;
      if (!vB) sB = i;
      float pax = pos[3 * sA], pay = pos[3 * sA + 1], paz = pos[3 * sA + 2];
      float pbx = pos[3 * sB], pby = pos[3 * sB + 1], pbz = pos[3 * sB + 2];
      edge4(sA, pax - px, pay - py, paz - pz, vA, xl_bf, l5, xr4, at4, w0, w1, w2, a0, a1, a2, a3, den);
      edge4(sB, pbx - px, pby - py, pbz - pz, vB, xl_bf, l5, xr4, at4, w0, w1, w2, a0, a1, a2, a3, den);
    }

    // combine the two half-wave partials
    den += __shfl_xor(den, 32);
    a0 += __shfl_xor(a0, 32);
    a1 += __shfl_xor(a1, 32);
    a2 += __shfl_xor(a2, 32);
    a3 += __shfl_xor(a3, 32);

    float inv = 1.f / (den + 1e-16f);
    if (half == 0) {
      float4 o = make_float4(a0 * inv, a1 * inv, a2 * inv, a3 * inv);
      *(float4*)(xr_out + i * HC + c) = o;   // overwrite xr row with pre-BN output
    }
  }
}

// ---------------------------------------------------------------- BN stats
__global__ __launch_bounds__(128) void k_bnstats(const float* __restrict__ out,
                                                 float* __restrict__ bn_sums) {
  int c = threadIdx.x;   // 128
  float s = 0.f, ss = 0.f;
  int r = blockIdx.x;
  const int g = gridDim.x;
  for (; r + g < N_NODES; r += 2 * g) {
    float v0 = out[r * HC + c];
    float v1 = out[(r + g) * HC + c];
    s += v0; ss = fmaf(v0, v0, ss);
    s += v1; ss = fmaf(v1, v1, ss);
  }
  if (r < N_NODES) {
    float v = out[r * HC + c];
    s += v; ss = fmaf(v, v, ss);
  }
  unsafeAtomicAdd(&bn_sums[c], s);
  unsafeAtomicAdd(&bn_sums[128 + c], ss);
}

// ---------------------------------------------------------------- BN apply (in place)
__global__ __launch_bounds__(256) void k_bnapply(float* __restrict__ out,
                                                 const float* __restrict__ bn_sums,
                                                 const float* __restrict__ gamma,
                                                 const float* __restrict__ beta,
                                                 int n4) {
  const int stride = gridDim.x * blockDim.x;
  const float invN = 1.f / (float)N_NODES;
  for (int i = blockIdx.x * blockDim.x + threadIdx.x; i < n4; i += stride) {
    int c = (i & 31) * 4;
    float4 v = ((float4*)out)[i];
    float4 s = *(const float4*)(bn_sums + c);
    float4 q = *(const float4*)(bn_sums + 128 + c);
    float4 g = *(const float4*)(gamma + c);
    float4 b = *(const float4*)(beta + c);
    float mu, var, rstd;
    mu = s.x * invN; var = q.x * invN - mu * mu; rstd = rsqrtf(var + BN_EPS);
    v.x = (v.x - mu) * rstd * g.x + b.x;
    mu = s.y * invN; var = q.y * invN - mu * mu; rstd = rsqrtf(var + BN_EPS);
    v.y = (v.y - mu) * rstd * g.y + b.y;
    mu = s.z * invN; var = q.z * invN - mu * mu; rstd = rsqrtf(var + BN_EPS);
    v.z = (v.z - mu) * rstd * g.z + b.z;
    mu = s.w * invN; var = q.w * invN - mu * mu; rstd = rsqrtf(var + BN_EPS);
    v.w = (v.w - mu) * rstd * g.w + b.w;
    ((float4*)out)[i] = v;
  }
}

extern "C" void kernel_launch(void* const* d_in, const int* in_sizes, int n_in,
                              void* d_out, int out_size, void* d_ws, size_t ws_size,
                              hipStream_t stream) {
  const float* x     = (const float*)d_in[0];
  const float* pos   = (const float*)d_in[1];
  const int*   eidx  = (const int*)d_in[2];
  const float* Wl    = (const float*)d_in[3];
  const float* Wr    = (const float*)d_in[4];
  const float* We    = (const float*)d_in[5];
  const float* att   = (const float*)d_in[6];
  const float* gamma = (const float*)d_in[7];
  const float* beta  = (const float*)d_in[8];
  float* out = (float*)d_out;
  const int E = in_sizes[2] / 2;

  char* ws = (char*)d_ws;
  int*   flag      = (int*)(ws + 0);
  float* mean_sums = (float*)(ws + 64);
  float* bn_sums   = (float*)(ws + 1024);
  int*   deg       = (int*)(ws + 4096);
  int*   ocnt      = (int*)(ws + (1 << 18));
  int*   srcs      = (int*)(ws + (1 << 19));
  unsigned int* xl_bf = (unsigned int*)(ws + (1 << 24));

  k_gemm<<<N_NODES / 16, 256, 0, stream>>>(x, Wl, Wr, xl_bf, out,
                                           deg, ocnt, mean_sums, bn_sums, flag, eidx);
  k_edges<<<1024, 256, 0, stream>>>(eidx, deg, ocnt, srcs, flag, E);
  k_nodemean<<<128, 256, 0, stream>>>(pos, deg, ocnt, mean_sums);
  k_agg<<<2048, 256, 0, stream>>>(xl_bf, out, pos, att, We, mean_sums, srcs, deg,
                                  1.f / (float)E);
  k_bnstats<<<512, 128, 0, stream>>>(out, bn_sums);
  k_bnapply<<<512, 256, 0, stream>>>(out, bn_sums, gamma, beta, out_size / 4);
}

// Round 4
// 256.605 us; speedup vs baseline: 1.4267x; 1.1258x over previous
//
#include <hip/hip_runtime.h>
#include <hip/hip_bf16.h>

#define N_NODES 50000
#define IN_CH 64
#define HC 128          // HEADS * OUT_CH
#define CAP 64          // per-node bucket capacity (incl. self-loop slot 0)
#define NEG_SLOPE 0.2f
#define BN_EPS 1e-5f

// ---- ws layout (bytes) ----
// 0       : int   flag_int64
// 64      : float mean_sums[3]
// 1024    : float bn_sums[256]   (sum[128], sumsq[128])
// 4096    : int   deg[N_NODES]           (indeg+1; slot 0 = self-loop)
// 1<<19   : int   srcs[N_NODES*CAP]      (12.8 MB)
// 1<<24   : uint  xl_bf[N_NODES*64]      (12.8 MB, bf16x2 per word)

// ---------------------------------------------------------------- gemm + fused init
__global__ __launch_bounds__(256) void k_gemm(const float* __restrict__ x,
                                              const float* __restrict__ Wl,
                                              const float* __restrict__ Wr,
                                              unsigned int* __restrict__ xl_bf,
                                              float* __restrict__ xr_out,
                                              int* __restrict__ deg,
                                              float* __restrict__ mean_sums,
                                              float* __restrict__ bn_sums,
                                              int* __restrict__ flag,
                                              const int* __restrict__ eidx) {
  // ---- fused init (independent of gemm work) ----
  {
    int gtid = blockIdx.x * 256 + threadIdx.x;
    if (gtid < N_NODES) deg[gtid] = 1;
    if (gtid < 256) bn_sums[gtid] = 0.f;
    if (gtid < 3) mean_sums[gtid] = 0.f;
    if (blockIdx.x == 0 && threadIdx.x < 64) {
      // int64 edge_index => odd 32-bit words (high words) all zero (indices < 50000)
      int w = eidx[2 * threadIdx.x + 1];
      unsigned long long nz = __ballot(w != 0);
      if (threadIdx.x == 0) flag[0] = (nz == 0ULL) ? 1 : 0;
    }
  }

  __shared__ float xs[16][IN_CH];                 // 4 KB
  __shared__ __hip_bfloat162 wsm[IN_CH][128];     // 32 KB
  const int t = threadIdx.x;
  const int row0 = blockIdx.x * 16;

  for (int i = 0; i < 32; ++i) {
    int k = i * 2 + (t >> 7);
    int p = t & 127;
    int cc = p * 2;
    float2 wv;
    if (cc < 128) wv = *(const float2*)(Wl + k * 128 + cc);
    else          wv = *(const float2*)(Wr + k * 128 + (cc - 128));
    wsm[k][p] = __float22bfloat162_rn(wv);
  }
  {
    int r = t >> 4, c4 = (t & 15) * 4;
    *(float4*)&xs[r][c4] = *(const float4*)(x + (row0 + r) * IN_CH + c4);
  }
  __syncthreads();

  const int ct = t & 63;
  const int rt = t >> 6;
  const int c4 = ct * 4;
  const int r4 = rt * 4;

  float acc[4][4];
  #pragma unroll
  for (int a = 0; a < 4; ++a)
    #pragma unroll
    for (int b = 0; b < 4; ++b) acc[a][b] = 0.f;

  #pragma unroll 8
  for (int k = 0; k < IN_CH; ++k) {
    uint2 wraw = *(const uint2*)&wsm[k][ct * 2];
    float2 f01 = __bfloat1622float2(*(__hip_bfloat162*)&wraw.x);
    float2 f23 = __bfloat1622float2(*(__hip_bfloat162*)&wraw.y);
    float wv[4] = {f01.x, f01.y, f23.x, f23.y};
    float xv[4] = {xs[r4][k], xs[r4 + 1][k], xs[r4 + 2][k], xs[r4 + 3][k]};
    #pragma unroll
    for (int a = 0; a < 4; ++a)
      #pragma unroll
      for (int b = 0; b < 4; ++b) acc[a][b] = fmaf(xv[a], wv[b], acc[a][b]);
  }

  #pragma unroll
  for (int a = 0; a < 4; ++a) {
    int row = row0 + r4 + a;
    if (c4 < 128) {
      __hip_bfloat162 b01 = __float22bfloat162_rn(make_float2(acc[a][0], acc[a][1]));
      __hip_bfloat162 b23 = __float22bfloat162_rn(make_float2(acc[a][2], acc[a][3]));
      uint2 u;
      u.x = *(unsigned int*)&b01;
      u.y = *(unsigned int*)&b23;
      *(uint2*)(xl_bf + row * 64 + (c4 >> 1)) = u;
    } else {
      float4 v = make_float4(acc[a][0], acc[a][1], acc[a][2], acc[a][3]);
      *(float4*)(xr_out + row * HC + (c4 - 128)) = v;
    }
  }
}

// ---------------------------------------------------------------- edge pass: 8 edges/thread, deep atomic MLP
__global__ __launch_bounds__(256) void k_edges(const int* __restrict__ eidx,
                                               const float* __restrict__ pos,
                                               int* __restrict__ deg,
                                               int* __restrict__ srcs,
                                               float* __restrict__ mean_sums,
                                               const int* __restrict__ flag,
                                               int E) {
  const bool w64 = flag[0] != 0;
  const int tid = blockIdx.x * 256 + threadIdx.x;
  const int base = tid * 8;
  float sx = 0.f, sy = 0.f, sz = 0.f;

  const bool vec_ok = w64 ? ((E & 1) == 0) : ((E & 3) == 0);

  if (base + 8 <= E && vec_ok) {
    int s[8], d[8];
    if (w64) {
      const int4* ps = (const int4*)(eidx + 2 * base);
      int4 A = ps[0], B = ps[1], C = ps[2], D = ps[3];
      s[0]=A.x; s[1]=A.z; s[2]=B.x; s[3]=B.z; s[4]=C.x; s[5]=C.z; s[6]=D.x; s[7]=D.z;
      const int4* pd = (const int4*)(eidx + 2 * E + 2 * base);
      A = pd[0]; B = pd[1]; C = pd[2]; D = pd[3];
      d[0]=A.x; d[1]=A.z; d[2]=B.x; d[3]=B.z; d[4]=C.x; d[5]=C.z; d[6]=D.x; d[7]=D.z;
    } else {
      int4 A = *(const int4*)(eidx + base);
      int4 B = *(const int4*)(eidx + base + 4);
      s[0]=A.x; s[1]=A.y; s[2]=A.z; s[3]=A.w; s[4]=B.x; s[5]=B.y; s[6]=B.z; s[7]=B.w;
      A = *(const int4*)(eidx + E + base);
      B = *(const int4*)(eidx + E + base + 4);
      d[0]=A.x; d[1]=A.y; d[2]=A.z; d[3]=A.w; d[4]=B.x; d[5]=B.y; d[6]=B.z; d[7]=B.w;
    }
    int slot[8];
    #pragma unroll
    for (int k = 0; k < 8; ++k) slot[k] = atomicAdd(&deg[d[k]], 1);
    #pragma unroll
    for (int k = 0; k < 8; ++k)
      if (slot[k] < CAP) srcs[d[k] * CAP + slot[k]] = s[k];
    #pragma unroll
    for (int k = 0; k < 8; ++k) {
      sx += pos[3 * s[k]]     - pos[3 * d[k]];
      sy += pos[3 * s[k] + 1] - pos[3 * d[k] + 1];
      sz += pos[3 * s[k] + 2] - pos[3 * d[k] + 2];
    }
  } else if (base < E) {
    int hi = min(base + 8, E);
    for (int e = base; e < hi; ++e) {
      int s, d;
      if (w64) { s = eidx[2 * e]; d = eidx[2 * (E + e)]; }
      else     { s = eidx[e];     d = eidx[E + e]; }
      int o = atomicAdd(&deg[d], 1);
      if (o < CAP) srcs[d * CAP + o] = s;
      sx += pos[3 * s]     - pos[3 * d];
      sy += pos[3 * s + 1] - pos[3 * d + 1];
      sz += pos[3 * s + 2] - pos[3 * d + 2];
    }
  }

  // block-wide reduction of the pos-diff sums
  #pragma unroll
  for (int m = 1; m < 64; m <<= 1) {
    sx += __shfl_xor(sx, m); sy += __shfl_xor(sy, m); sz += __shfl_xor(sz, m);
  }
  __shared__ float red[4][3];
  int wave = threadIdx.x >> 6, lane = threadIdx.x & 63;
  if (lane == 0) { red[wave][0] = sx; red[wave][1] = sy; red[wave][2] = sz; }
  __syncthreads();
  if (threadIdx.x == 0) {
    float a = 0.f, b = 0.f, c = 0.f;
    for (int w = 0; w < 4; ++w) { a += red[w][0]; b += red[w][1]; c += red[w][2]; }
    unsafeAtomicAdd(&mean_sums[0], a);
    unsafeAtomicAdd(&mean_sums[1], b);
    unsafeAtomicAdd(&mean_sums[2], c);
  }
}

// ---------------------------------------------------------------- per-edge (half-wave, 4 ch/lane) helper
__device__ __forceinline__ void edge4(int s, float dx, float dy, float dz, bool valid,
                                      const unsigned int* __restrict__ xl_bf, int l5,
                                      float4 xr4, float4 at4, float4 w0, float4 w1, float4 w2,
                                      float& a0, float& a1, float& a2, float& a3, float& den) {
  uint2 raw = *(const uint2*)(xl_bf + (s << 6) + (l5 << 1));
  float2 x01 = __bfloat1622float2(*(__hip_bfloat162*)&raw.x);
  float2 x23 = __bfloat1622float2(*(__hip_bfloat162*)&raw.y);
  float t0 = x01.x + xr4.x; t0 = fmaf(dx, w0.x, t0); t0 = fmaf(dy, w1.x, t0); t0 = fmaf(dz, w2.x, t0);
  float t1 = x01.y + xr4.y; t1 = fmaf(dx, w0.y, t1); t1 = fmaf(dy, w1.y, t1); t1 = fmaf(dz, w2.y, t1);
  float t2 = x23.x + xr4.z; t2 = fmaf(dx, w0.z, t2); t2 = fmaf(dy, w1.z, t2); t2 = fmaf(dz, w2.z, t2);
  float t3 = x23.y + xr4.w; t3 = fmaf(dx, w0.w, t3); t3 = fmaf(dy, w1.w, t3); t3 = fmaf(dz, w2.w, t3);
  float l0 = fmaf(NEG_SLOPE, fminf(t0, 0.f), fmaxf(t0, 0.f));
  float l1 = fmaf(NEG_SLOPE, fminf(t1, 0.f), fmaxf(t1, 0.f));
  float l2 = fmaf(NEG_SLOPE, fminf(t2, 0.f), fmaxf(t2, 0.f));
  float l3 = fmaf(NEG_SLOPE, fminf(t3, 0.f), fmaxf(t3, 0.f));
  float sc = l0 * at4.x;
  sc = fmaf(l1, at4.y, sc); sc = fmaf(l2, at4.z, sc); sc = fmaf(l3, at4.w, sc);
  sc += __shfl_xor(sc, 1); sc += __shfl_xor(sc, 2); sc += __shfl_xor(sc, 4);  // 8 lanes = 1 head
  float e = __expf(sc);
  float p = valid ? e : 0.f;
  den += p;
  a0 = fmaf(p, x01.x, a0); a1 = fmaf(p, x01.y, a1);
  a2 = fmaf(p, x23.x, a2); a3 = fmaf(p, x23.y, a3);
}

// ---------------------------------------------------------------- one wave = 2 edges at a time, persistent over nodes
__global__ __launch_bounds__(256) void k_agg(const unsigned int* __restrict__ xl_bf,
                                             float* __restrict__ xr_out,   // in: xr, out: pre-BN out
                                             const float* __restrict__ pos,
                                             const float* __restrict__ att,
                                             const float* __restrict__ We,
                                             const float* __restrict__ mean_sums,
                                             const int* __restrict__ srcs,
                                             const int* __restrict__ deg,
                                             float invE) {
  const int lane = threadIdx.x & 63;
  const int half = lane >> 5;
  const int l5 = lane & 31;
  const int c = l5 << 2;               // 4 channels per lane; head = l5>>3

  const float4 at4 = *(const float4*)(att + c);
  const float4 w0 = *(const float4*)(We + c);
  const float4 w1 = *(const float4*)(We + 128 + c);
  const float4 w2 = *(const float4*)(We + 256 + c);
  const float m0 = mean_sums[0] * invE;
  const float m1 = mean_sums[1] * invE;
  const float m2 = mean_sums[2] * invE;

  const int gw = blockIdx.x * 4 + (threadIdx.x >> 6);
  const int W = gridDim.x * 4;

  for (int i = gw; i < N_NODES; i += W) {
    const float4 xr4 = *(const float4*)(xr_out + i * HC + c);
    const float px = pos[3 * i], py = pos[3 * i + 1], pz = pos[3 * i + 2];
    const int di = min(deg[i], CAP);
    const int sreg = srcs[i * CAP + lane];   // whole bucket row staged in registers
    float a0 = 0.f, a1 = 0.f, a2 = 0.f, a3 = 0.f, den = 0.f;

    // peeled first iteration: slots 0..3 (slot 0 = self-loop, dx = mean_attr)
    {
      int sA = __shfl(sreg, 1);
      if (half == 0) sA = i;
      bool vA = half < di;
      if (!vA) sA = i;
      int jB = 2 + half;
      int sB = __shfl(sreg, jB);
      bool vB = jB < di;
      if (!vB) sB = i;
      float pax = pos[3 * sA], pay = pos[3 * sA + 1], paz = pos[3 * sA + 2];
      float pbx = pos[3 * sB], pby = pos[3 * sB + 1], pbz = pos[3 * sB + 2];
      float dxA = (half == 0) ? m0 : pax - px;
      float dyA = (half == 0) ? m1 : pay - py;
      float dzA = (half == 0) ? m2 : paz - pz;
      edge4(sA, dxA, dyA, dzA, vA, xl_bf, l5, xr4, at4, w0, w1, w2, a0, a1, a2, a3, den);
      edge4(sB, pbx - px, pby - py, pbz - pz, vB, xl_bf, l5, xr4, at4, w0, w1, w2, a0, a1, a2, a3, den);
    }

    for (int j = 4; j < di; j += 4) {
      int jA = j + half;
      int jB = j + 2 + half;
      int sA = __shfl(sreg, jA);
      int sB = __shfl(sreg, jB);
      bool vA = jA < di;
      bool vB = jB < di;
      if (!vA) sA = i;
      if (!vB) sB = i;
      float pax = pos[3 * sA], pay = pos[3 * sA + 1], paz = pos[3 * sA + 2];
      float pbx = pos[3 * sB], pby = pos[3 * sB + 1], pbz = pos[3 * sB + 2];
      edge4(sA, pax - px, pay - py, paz - pz, vA, xl_bf, l5, xr4, at4, w0, w1, w2, a0, a1, a2, a3, den);
      edge4(sB, pbx - px, pby - py, pbz - pz, vB, xl_bf, l5, xr4, at4, w0, w1, w2, a0, a1, a2, a3, den);
    }

    den += __shfl_xor(den, 32);
    a0 += __shfl_xor(a0, 32);
    a1 += __shfl_xor(a1, 32);
    a2 += __shfl_xor(a2, 32);
    a3 += __shfl_xor(a3, 32);

    float inv = 1.f / (den + 1e-16f);
    if (half == 0) {
      float4 o = make_float4(a0 * inv, a1 * inv, a2 * inv, a3 * inv);
      *(float4*)(xr_out + i * HC + c) = o;   // overwrite xr row with pre-BN output
    }
  }
}

// ---------------------------------------------------------------- BN stats
__global__ __launch_bounds__(128) void k_bnstats(const float* __restrict__ out,
                                                 float* __restrict__ bn_sums) {
  int c = threadIdx.x;   // 128
  float s = 0.f, ss = 0.f;
  int r = blockIdx.x;
  const int g = gridDim.x;
  for (; r + g < N_NODES; r += 2 * g) {
    float v0 = out[r * HC + c];
    float v1 = out[(r + g) * HC + c];
    s += v0; ss = fmaf(v0, v0, ss);
    s += v1; ss = fmaf(v1, v1, ss);
  }
  if (r < N_NODES) {
    float v = out[r * HC + c];
    s += v; ss = fmaf(v, v, ss);
  }
  unsafeAtomicAdd(&bn_sums[c], s);
  unsafeAtomicAdd(&bn_sums[128 + c], ss);
}

// ---------------------------------------------------------------- BN apply (in place)
__global__ __launch_bounds__(256) void k_bnapply(float* __restrict__ out,
                                                 const float* __restrict__ bn_sums,
                                                 const float* __restrict__ gamma,
                                                 const float* __restrict__ beta,
                                                 int n4) {
  const int stride = gridDim.x * blockDim.x;
  const float invN = 1.f / (float)N_NODES;
  for (int i = blockIdx.x * blockDim.x + threadIdx.x; i < n4; i += stride) {
    int c = (i & 31) * 4;
    float4 v = ((float4*)out)[i];
    float4 s = *(const float4*)(bn_sums + c);
    float4 q = *(const float4*)(bn_sums + 128 + c);
    float4 g = *(const float4*)(gamma + c);
    float4 b = *(const float4*)(beta + c);
    float mu, var, rstd;
    mu = s.x * invN; var = q.x * invN - mu * mu; rstd = rsqrtf(var + BN_EPS);
    v.x = (v.x - mu) * rstd * g.x + b.x;
    mu = s.y * invN; var = q.y * invN - mu * mu; rstd = rsqrtf(var + BN_EPS);
    v.y = (v.y - mu) * rstd * g.y + b.y;
    mu = s.z * invN; var = q.z * invN - mu * mu; rstd = rsqrtf(var + BN_EPS);
    v.z = (v.z - mu) * rstd * g.z + b.z;
    mu = s.w * invN; var = q.w * invN - mu * mu; rstd = rsqrtf(var + BN_EPS);
    v.w = (v.w - mu) * rstd * g.w + b.w;
    ((float4*)out)[i] = v;
  }
}

extern "C" void kernel_launch(void* const* d_in, const int* in_sizes, int n_in,
                              void* d_out, int out_size, void* d_ws, size_t ws_size,
                              hipStream_t stream) {
  const float* x     = (const float*)d_in[0];
  const float* pos   = (const float*)d_in[1];
  const int*   eidx  = (const int*)d_in[2];
  const float* Wl    = (const float*)d_in[3];
  const float* Wr    = (const float*)d_in[4];
  const float* We    = (const float*)d_in[5];
  const float* att   = (const float*)d_in[6];
  const float* gamma = (const float*)d_in[7];
  const float* beta  = (const float*)d_in[8];
  float* out = (float*)d_out;
  const int E = in_sizes[2] / 2;

  char* ws = (char*)d_ws;
  int*   flag      = (int*)(ws + 0);
  float* mean_sums = (float*)(ws + 64);
  float* bn_sums   = (float*)(ws + 1024);
  int*   deg       = (int*)(ws + 4096);
  int*   srcs      = (int*)(ws + (1 << 19));
  unsigned int* xl_bf = (unsigned int*)(ws + (1 << 24));

  k_gemm<<<N_NODES / 16, 256, 0, stream>>>(x, Wl, Wr, xl_bf, out,
                                           deg, mean_sums, bn_sums, flag, eidx);
  int eblocks = (E + 2047) / 2048;   // 8 edges per thread
  k_edges<<<eblocks, 256, 0, stream>>>(eidx, pos, deg, srcs, mean_sums, flag, E);
  k_agg<<<2048, 256, 0, stream>>>(xl_bf, out, pos, att, We, mean_sums, srcs, deg,
                                  1.f / (float)E);
  k_bnstats<<<512, 128, 0, stream>>>(out, bn_sums);
  k_bnapply<<<512, 256, 0, stream>>>(out, bn_sums, gamma, beta, out_size / 4);
}